// Round 1
// baseline (222.570 us; speedup 1.0000x reference)
//
#include <hip/hip_runtime.h>
#include <hip/hip_bf16.h>

#define NB 8
#define N1 4096
#define N2 768

__device__ __forceinline__ float2 cadd(float2 a, float2 b){ return make_float2(a.x+b.x, a.y+b.y); }
__device__ __forceinline__ float2 csub(float2 a, float2 b){ return make_float2(a.x-b.x, a.y-b.y); }
__device__ __forceinline__ float2 cmul(float2 a, float2 b){ return make_float2(a.x*b.x - a.y*b.y, a.x*b.y + a.y*b.x); }
__device__ __forceinline__ float2 cnegi(float2 a){ return make_float2(a.y, -a.x); }  // -i * a

// radix-4 DIF butterfly, in-place, with twiddles W_{4M}^{r*np}
__device__ __forceinline__ void bfly4(float2* arr, int base, int M, float fac, int np) {
  float2 a0 = arr[base], a1 = arr[base+M], a2 = arr[base+2*M], a3 = arr[base+3*M];
  float2 t0 = cadd(a0,a2), t1 = csub(a0,a2);
  float2 t2 = cadd(a1,a3), t3 = cnegi(csub(a1,a3));
  float2 y0 = cadd(t0,t2), y1 = cadd(t1,t3), y2 = csub(t0,t2), y3 = csub(t1,t3);
  float ang = fac * (float)np;
  float sn, cs; __sincosf(ang, &sn, &cs);
  float2 w1 = make_float2(cs, sn);
  float2 w2 = cmul(w1,w1);
  float2 w3 = cmul(w2,w1);
  arr[base]     = y0;
  arr[base+M]   = cmul(y1,w1);
  arr[base+2*M] = cmul(y2,w2);
  arr[base+3*M] = cmul(y3,w3);
}

// Pass 1: 4096-pt FFT along seq axis (stride N2) of the real input.
// Output packed into d_out using Hermitian symmetry:
//   row k (k<=2048): Re X[k];  row k (k>2048): Im X[4096-k]  (= -Im X[k]).
// 2 adjacent columns per block (float2 global accesses), 64 KB dynamic LDS.
__global__ __launch_bounds__(256) void fft_seq_kernel(const float* __restrict__ x,
                                                      float* __restrict__ out) {
  extern __shared__ float2 lds[];   // 2 columns * 4096 complex = 64 KB
  // XCD-aware swizzle: blocks 8 apart share an XCD; give them consecutive work
  int bid = blockIdx.x;                       // 0..3071 (divisible by 8)
  int wg  = (bid & 7) * (3072/8) + (bid >> 3);
  int b    = wg / (N2/2);
  int g    = wg % (N2/2);
  int n2_0 = g * 2;
  const int t = threadIdx.x;

  const float* src = x + (size_t)b * N1 * N2 + n2_0;
  for (int n1 = t; n1 < N1; n1 += 256) {
    float2 v = *reinterpret_cast<const float2*>(src + (size_t)n1 * N2);
    lds[n1]      = make_float2(v.x, 0.0f);
    lds[N1 + n1] = make_float2(v.y, 0.0f);
  }
  __syncthreads();

  float2* a = lds + (t >> 7) * N1;   // 128 threads per column
  int tid = t & 127;
  #pragma unroll
  for (int s = 0; s < 6; ++s) {      // 4096 = 4^6
    int lm = 10 - 2*s;               // log2(M): 10,8,6,4,2,0
    int M  = 1 << lm;
    float fac = -6.283185307179586f / (float)(4*M);
    for (int j = tid; j < 1024; j += 128) {
      int np  = j & (M-1);
      int grp = j >> lm;
      int base = (grp << (lm+2)) + np;
      bfly4(a, base, M, fac, np);
    }
    __syncthreads();
  }

  // packed write (digit-reversed order -> natural k)
  float* orow = out + (size_t)b * N1 * N2 + n2_0;
  for (int p = t; p < N1; p += 256) {
    int k = 0, pp = p;
    #pragma unroll
    for (int i = 0; i < 6; ++i) { k = (k<<2) | (pp & 3); pp >>= 2; }
    float2 v0 = lds[p], v1 = lds[N1 + p];
    float o0 = (k <= 2048) ? v0.x : -v0.y;
    float o1 = (k <= 2048) ? v1.x : -v1.y;
    *reinterpret_cast<float2*>(orow + (size_t)k * N2) = make_float2(o0, o1);
  }
}

// Pass 2: 768-pt FFT along hidden axis. One task per conjugate row pair
// (t1, 4096-t1); rows 0 and 2048 are real-only specials.
// 768 = 3 * 256: three 256-pt radix-4 FFTs over x[3n'+q], then radix-3 combine.
// 4 tasks per 256-thread block (64 lanes each). Total tasks = 8*2049 = 16392.
__global__ __launch_bounds__(256) void fft_hid_kernel(float* __restrict__ out) {
  __shared__ float2 buf[4][768];   // 24 KB
  const int grp = threadIdx.x >> 6;
  const int tid = threadIdx.x & 63;
  int task = blockIdx.x * 4 + grp;            // < 16392 exactly (4098*4)
  int b  = task / 2049;
  int t1 = task - b * 2049;                   // 0..2048
  const bool special = (t1 == 0) || (t1 == 2048);
  float* baseB = out + (size_t)b * N1 * N2;
  float* pre = baseB + (size_t)t1 * N2;            // Re X[t1]
  float* pim = baseB + (size_t)(N1 - t1) * N2;     // Im X[t1] (packed row)
  float2* Bf = buf[grp];

  for (int n = tid; n < N2; n += 64) {
    int np = n / 3;
    int q  = n - 3*np;
    float re = pre[n];
    float im = special ? 0.0f : pim[n];
    Bf[q*256 + np] = make_float2(re, im);
  }
  __syncthreads();

  #pragma unroll
  for (int s = 0; s < 4; ++s) {     // 256 = 4^4, three independent sub-FFTs
    int lm = 6 - 2*s;               // log2(M): 6,4,2,0
    int M  = 1 << lm;
    float fac = -6.283185307179586f / (float)(4*M);
    for (int j = tid; j < 192; j += 64) {
      int sub = j >> 6;
      int jj  = j & 63;
      int np  = jj & (M-1);
      int gi  = jj >> lm;
      int base = sub*256 + (gi << (lm+2)) + np;
      bfly4(Bf, base, M, fac, np);
    }
    __syncthreads();
  }

  // combine: X[k] = Y0[j] + W^k Y1[j] + W^2k Y2[j],  j = k mod 256 (digit-reversed)
  for (int k = tid; k < N2; k += 64) {
    int j = k & 255;
    int jr = 0, pp = j;
    #pragma unroll
    for (int i = 0; i < 4; ++i) { jr = (jr<<2) | (pp & 3); pp >>= 2; }
    float2 y0 = Bf[jr], y1 = Bf[256 + jr], y2 = Bf[512 + jr];
    float ang = -6.283185307179586f * (float)k / 768.0f;
    float sn, cs; __sincosf(ang, &sn, &cs);
    float2 w  = make_float2(cs, sn);
    float2 w2 = cmul(w, w);
    float rey = y0.x + (w.x*y1.x - w.y*y1.y) + (w2.x*y2.x - w2.y*y2.y);
    pre[k] = rey;                                // out row t1
    if (!special) {
      int km = (k == 0) ? 0 : (N2 - k);
      pim[km] = rey;                             // out row 4096-t1 (mirrored)
    }
  }
}

extern "C" void kernel_launch(void* const* d_in, const int* in_sizes, int n_in,
                              void* d_out, int out_size, void* d_ws, size_t ws_size,
                              hipStream_t stream) {
  const float* x = (const float*)d_in[0];
  float* out = (float*)d_out;
  fft_seq_kernel<<<dim3(3072), dim3(256), 65536, stream>>>(x, out);
  fft_hid_kernel<<<dim3(4098), dim3(256), 0, stream>>>(out);
}

// Round 2
// 215.433 us; speedup vs baseline: 1.0331x; 1.0331x over previous
//
#include <hip/hip_runtime.h>
#include <hip/hip_bf16.h>

#define NB 8
#define N1 4096
#define N2 768
#define PADI(i) ((i) + ((i) >> 4))

__device__ __forceinline__ float2 cadd(float2 a, float2 b){ return make_float2(a.x+b.x, a.y+b.y); }
__device__ __forceinline__ float2 csub(float2 a, float2 b){ return make_float2(a.x-b.x, a.y-b.y); }
__device__ __forceinline__ float2 cmul(float2 a, float2 b){ return make_float2(a.x*b.x - a.y*b.y, a.x*b.y + a.y*b.x); }
__device__ __forceinline__ float2 cnegi(float2 a){ return make_float2(a.y, -a.x); }  // -i * a

__device__ __forceinline__ int rev6(int p) {  // 6-digit base-4 reversal (12 bits)
  int k = 0;
  #pragma unroll
  for (int i = 0; i < 6; ++i) { k = (k << 2) | (p & 3); p >>= 2; }
  return k;
}

// radix-4 DIF butterfly on padded LDS, twiddles W_{4M}^{r*np}
__device__ __forceinline__ void bfly4p(float2* arr, int base, int M, float fac, int np) {
  float2 a0 = arr[PADI(base)], a1 = arr[PADI(base+M)];
  float2 a2 = arr[PADI(base+2*M)], a3 = arr[PADI(base+3*M)];
  float2 t0 = cadd(a0,a2), t1 = csub(a0,a2);
  float2 t2 = cadd(a1,a3), t3 = cnegi(csub(a1,a3));
  float2 y0 = cadd(t0,t2), y1 = cadd(t1,t3), y2 = csub(t0,t2), y3 = csub(t1,t3);
  float ang = fac * (float)np;
  float sn, cs; __sincosf(ang, &sn, &cs);
  float2 w1 = make_float2(cs, sn);
  float2 w2 = cmul(w1,w1);
  float2 w3 = cmul(w2,w1);
  arr[PADI(base)]     = y0;
  arr[PADI(base+M)]   = cmul(y1,w1);
  arr[PADI(base+2*M)] = cmul(y2,w2);
  arr[PADI(base+3*M)] = cmul(y3,w3);
}

// Pass 1: 4096-pt FFT along seq axis. TWO real columns packed as one complex
// FFT (re = col n2_0, im = col n2_0+1). Unpack via Hermitian symmetry into the
// packed d_out format: row k (k<=2048): Re X[k]; row k (>2048): Im X[4096-k].
__global__ __launch_bounds__(256) void fft_seq_kernel(const float* __restrict__ x,
                                                      float* __restrict__ out) {
  __shared__ float2 lds[PADI(N1 - 1) + 1 + 1];   // 4096 + 255 pad  (~34 KB)
  int bid = blockIdx.x;                      // 0..3071
  int wg  = (bid & 7) * (3072 / 8) + (bid >> 3);   // XCD swizzle
  int b    = wg / (N2/2);
  int g    = wg % (N2/2);
  int n2_0 = g * 2;
  const int t = threadIdx.x;

  const float* src = x + (size_t)b * N1 * N2 + n2_0;
  for (int n1 = t; n1 < N1; n1 += 256) {
    float2 v = *reinterpret_cast<const float2*>(src + (size_t)n1 * N2);
    lds[PADI(n1)] = v;                        // complex = (col0, col1)
  }
  __syncthreads();

  #pragma unroll
  for (int s = 0; s < 6; ++s) {      // 4096 = 4^6
    int lm = 10 - 2*s;               // log2(M): 10,8,6,4,2,0
    int M  = 1 << lm;
    float fac = -6.283185307179586f / (float)(4*M);
    for (int j = t; j < 1024; j += 256) {
      int np  = j & (M-1);
      int grp = j >> lm;
      int base = (grp << (lm+2)) + np;
      bfly4p(lds, base, M, fac, np);
    }
    __syncthreads();
  }

  // unpack + packed write (position p holds Z[rev6(p)])
  float* orow = out + (size_t)b * N1 * N2 + n2_0;
  for (int p = t; p < N1; p += 256) {
    int k  = rev6(p);
    int km = (N1 - k) & (N1 - 1);
    float2 zk = lds[PADI(p)];
    float2 zn = lds[PADI(rev6(km))];
    float2 o;
    if (k <= 2048) o = make_float2(0.5f*(zk.x + zn.x), 0.5f*(zk.y + zn.y));
    else           o = make_float2(0.5f*(zn.y - zk.y), 0.5f*(zk.x - zn.x));
    *reinterpret_cast<float2*>(orow + (size_t)k * N2) = o;
  }
}

// Pass 2: 768-pt FFT along hidden axis, one task per conjugate row pair.
__global__ __launch_bounds__(256) void fft_hid_kernel(float* __restrict__ out) {
  __shared__ float2 buf[4][768];   // 24 KB
  const int grp = threadIdx.x >> 6;
  const int tid = threadIdx.x & 63;
  int task = blockIdx.x * 4 + grp;            // < 16392 exactly (4098*4)
  int b  = task / 2049;
  int t1 = task - b * 2049;                   // 0..2048
  const bool special = (t1 == 0) || (t1 == 2048);
  float* baseB = out + (size_t)b * N1 * N2;
  float* pre = baseB + (size_t)t1 * N2;            // Re X[t1]
  float* pim = baseB + (size_t)(N1 - t1) * N2;     // Im X[t1] (packed row)
  float2* Bf = buf[grp];

  for (int n = tid; n < N2; n += 64) {
    int np = n / 3;
    int q  = n - 3*np;
    float re = pre[n];
    float im = special ? 0.0f : pim[n];
    Bf[q*256 + np] = make_float2(re, im);
  }
  __syncthreads();

  #pragma unroll
  for (int s = 0; s < 4; ++s) {     // 256 = 4^4, three independent sub-FFTs
    int lm = 6 - 2*s;               // log2(M): 6,4,2,0
    int M  = 1 << lm;
    float fac = -6.283185307179586f / (float)(4*M);
    for (int j = tid; j < 192; j += 64) {
      int sub = j >> 6;
      int jj  = j & 63;
      int np  = jj & (M-1);
      int gi  = jj >> lm;
      int base = sub*256 + (gi << (lm+2)) + np;
      float2 a0 = Bf[base], a1 = Bf[base+M], a2 = Bf[base+2*M], a3 = Bf[base+3*M];
      float2 t0 = cadd(a0,a2), t1v = csub(a0,a2);
      float2 t2 = cadd(a1,a3), t3 = cnegi(csub(a1,a3));
      float2 y0 = cadd(t0,t2), y1 = cadd(t1v,t3), y2 = csub(t0,t2), y3 = csub(t1v,t3);
      float ang = fac * (float)np;
      float sn, cs; __sincosf(ang, &sn, &cs);
      float2 w1 = make_float2(cs, sn);
      float2 w2 = cmul(w1,w1);
      float2 w3 = cmul(w2,w1);
      Bf[base]     = y0;
      Bf[base+M]   = cmul(y1,w1);
      Bf[base+2*M] = cmul(y2,w2);
      Bf[base+3*M] = cmul(y3,w3);
    }
    __syncthreads();
  }

  // combine: X[k] = Y0[j] + W^k Y1[j] + W^2k Y2[j],  j = k mod 256 (digit-reversed)
  for (int k = tid; k < N2; k += 64) {
    int j = k & 255;
    int jr = 0, pp = j;
    #pragma unroll
    for (int i = 0; i < 4; ++i) { jr = (jr<<2) | (pp & 3); pp >>= 2; }
    float2 y0 = Bf[jr], y1 = Bf[256 + jr], y2 = Bf[512 + jr];
    float ang = -6.283185307179586f * (float)k / 768.0f;
    float sn, cs; __sincosf(ang, &sn, &cs);
    float2 w  = make_float2(cs, sn);
    float2 w2 = cmul(w, w);
    float rey = y0.x + (w.x*y1.x - w.y*y1.y) + (w2.x*y2.x - w2.y*y2.y);
    pre[k] = rey;                                // out row t1
    if (!special) {
      int km = (k == 0) ? 0 : (N2 - k);
      pim[km] = rey;                             // out row 4096-t1 (mirrored)
    }
  }
}

extern "C" void kernel_launch(void* const* d_in, const int* in_sizes, int n_in,
                              void* d_out, int out_size, void* d_ws, size_t ws_size,
                              hipStream_t stream) {
  const float* x = (const float*)d_in[0];
  float* out = (float*)d_out;
  fft_seq_kernel<<<dim3(3072), dim3(256), 0, stream>>>(x, out);
  fft_hid_kernel<<<dim3(4098), dim3(256), 0, stream>>>(out);
}

// Round 3
// 177.845 us; speedup vs baseline: 1.2515x; 1.2114x over previous
//
#include <hip/hip_runtime.h>
#include <hip/hip_bf16.h>

#define N1 4096
#define N2 768
#define PADI(i) ((i) + ((i) >> 4))
#define CPBUF 4352   // PADI(4095)=4350 -> 4351 floats2, padded to 4352

__device__ __forceinline__ float2 cadd(float2 a, float2 b){ return make_float2(a.x+b.x, a.y+b.y); }
__device__ __forceinline__ float2 csub(float2 a, float2 b){ return make_float2(a.x-b.x, a.y-b.y); }
__device__ __forceinline__ float2 cmul(float2 a, float2 b){ return make_float2(a.x*b.x - a.y*b.y, a.x*b.y + a.y*b.x); }
__device__ __forceinline__ float2 cnegi(float2 a){ return make_float2(a.y, -a.x); }  // -i * a

__device__ __forceinline__ int rev6(int p) {  // 6-digit base-4 reversal
  int k = 0;
  #pragma unroll
  for (int i = 0; i < 6; ++i) { k = (k << 2) | (p & 3); p >>= 2; }
  return k;
}

// radix-4 DIF butterfly on padded LDS, twiddles W_{4M}^{r*np}
__device__ __forceinline__ void bfly4p(float2* arr, int base, int M, float fac, int np) {
  float2 a0 = arr[PADI(base)], a1 = arr[PADI(base+M)];
  float2 a2 = arr[PADI(base+2*M)], a3 = arr[PADI(base+3*M)];
  float2 t0 = cadd(a0,a2), t1 = csub(a0,a2);
  float2 t2 = cadd(a1,a3), t3 = cnegi(csub(a1,a3));
  float2 y0 = cadd(t0,t2), y1 = cadd(t1,t3), y2 = csub(t0,t2), y3 = csub(t1,t3);
  float ang = fac * (float)np;
  float sn, cs; __sincosf(ang, &sn, &cs);
  float2 w1 = make_float2(cs, sn);
  float2 w2 = cmul(w1,w1);
  float2 w3 = cmul(w2,w1);
  arr[PADI(base)]     = y0;
  arr[PADI(base+M)]   = cmul(y1,w1);
  arr[PADI(base+2*M)] = cmul(y2,w2);
  arr[PADI(base+3*M)] = cmul(y3,w3);
}

// Fused pass 1: one block = 8 consecutive hidden-columns = 4 packed complex
// 4096-pt FFTs in 139 KB dynamic LDS. Coalesced 32 B/row loads and stores.
// Output packed Hermitian: row k<=2048: Re X[k]; row k>2048: Im X[4096-k].
__global__ __launch_bounds__(1024) void fft_seq_fused(const float* __restrict__ x,
                                                      float* __restrict__ out) {
  extern __shared__ float2 lds[];            // 4 * CPBUF float2
  int bid = blockIdx.x;                      // 0..767
  int wg  = (bid & 7) * 96 + (bid >> 3);     // XCD swizzle (768 = 8*96)
  int b   = wg / 96;
  int g   = wg % 96;
  const int t = threadIdx.x;
  const size_t base = (size_t)b * N1 * N2 + 8 * (size_t)g;

  // Load: 4 rows/thread, 2 adjacent float4 per row (32 B contiguous)
  for (int r = t; r < N1; r += 1024) {
    const float* p = x + base + (size_t)r * N2;
    float4 A  = *reinterpret_cast<const float4*>(p);
    float4 Bv = *reinterpret_cast<const float4*>(p + 4);
    int ip = PADI(r);
    lds[ip]             = make_float2(A.x, A.y);
    lds[CPBUF + ip]     = make_float2(A.z, A.w);
    lds[2*CPBUF + ip]   = make_float2(Bv.x, Bv.y);
    lds[3*CPBUF + ip]   = make_float2(Bv.z, Bv.w);
  }
  __syncthreads();

  // FFT: 16 waves; colpair cp = wave&3; 4 waves (256 threads) per colpair
  const int wv  = t >> 6;                    // 0..15
  const int cp  = wv & 3;
  const int idx = ((wv >> 2) << 6) + (t & 63);  // 0..255 in colpair team
  float2* buf = lds + cp * CPBUF;

  #pragma unroll
  for (int s = 0; s < 6; ++s) {              // 4096 = 4^6
    int lm = 10 - 2*s;                       // log2(M)
    int M  = 1 << lm;
    float fac = -6.283185307179586f / (float)(4*M);
    #pragma unroll
    for (int jj = 0; jj < 4; ++jj) {
      int j   = idx + (jj << 8);
      int np  = j & (M-1);
      int grp = j >> lm;
      int bse = (grp << (lm+2)) + np;
      bfly4p(buf, bse, M, fac, np);
    }
    __syncthreads();
  }

  // Store: k = lane*64 + wv + 16i keeps LDS reads contiguous per wave.
  float* orow = out + base;
  #pragma unroll
  for (int i = 0; i < 4; ++i) {
    int k  = ((t & 63) << 6) + (t >> 6) + (i << 4);
    int km = (N1 - k) & (N1 - 1);
    int pk = PADI(rev6(k));
    int pn = PADI(rev6(km));
    float o[8];
    #pragma unroll
    for (int c = 0; c < 4; ++c) {
      float2 zk = lds[c*CPBUF + pk];
      float2 zn = lds[c*CPBUF + pn];
      if (k <= 2048) { o[2*c] = 0.5f*(zk.x + zn.x); o[2*c+1] = 0.5f*(zk.y + zn.y); }
      else           { o[2*c] = 0.5f*(zn.y - zk.y); o[2*c+1] = 0.5f*(zk.x - zn.x); }
    }
    float* q = orow + (size_t)k * N2;
    *reinterpret_cast<float4*>(q)     = make_float4(o[0], o[1], o[2], o[3]);
    *reinterpret_cast<float4*>(q + 4) = make_float4(o[4], o[5], o[6], o[7]);
  }
}

// Pass 2: 768-pt FFT along hidden axis, one task per conjugate row pair.
__global__ __launch_bounds__(256) void fft_hid_kernel(float* __restrict__ out) {
  __shared__ float2 buf[4][768];   // 24 KB
  const int grp = threadIdx.x >> 6;
  const int tid = threadIdx.x & 63;
  int task = blockIdx.x * 4 + grp;            // < 16392 exactly (4098*4)
  int b  = task / 2049;
  int t1 = task - b * 2049;                   // 0..2048
  const bool special = (t1 == 0) || (t1 == 2048);
  float* baseB = out + (size_t)b * N1 * N2;
  float* pre = baseB + (size_t)t1 * N2;            // Re X[t1]
  float* pim = baseB + (size_t)(N1 - t1) * N2;     // Im X[t1] (packed row)
  float2* Bf = buf[grp];

  for (int n = tid; n < N2; n += 64) {
    int np = n / 3;
    int q  = n - 3*np;
    float re = pre[n];
    float im = special ? 0.0f : pim[n];
    Bf[q*256 + np] = make_float2(re, im);
  }
  __syncthreads();

  #pragma unroll
  for (int s = 0; s < 4; ++s) {     // 256 = 4^4, three independent sub-FFTs
    int lm = 6 - 2*s;               // log2(M): 6,4,2,0
    int M  = 1 << lm;
    float fac = -6.283185307179586f / (float)(4*M);
    for (int j = tid; j < 192; j += 64) {
      int sub = j >> 6;
      int jj  = j & 63;
      int np  = jj & (M-1);
      int gi  = jj >> lm;
      int bse = sub*256 + (gi << (lm+2)) + np;
      float2 a0 = Bf[bse], a1 = Bf[bse+M], a2 = Bf[bse+2*M], a3 = Bf[bse+3*M];
      float2 t0 = cadd(a0,a2), t1v = csub(a0,a2);
      float2 t2 = cadd(a1,a3), t3 = cnegi(csub(a1,a3));
      float2 y0 = cadd(t0,t2), y1 = cadd(t1v,t3), y2 = csub(t0,t2), y3 = csub(t1v,t3);
      float ang = fac * (float)np;
      float sn, cs; __sincosf(ang, &sn, &cs);
      float2 w1 = make_float2(cs, sn);
      float2 w2 = cmul(w1,w1);
      float2 w3 = cmul(w2,w1);
      Bf[bse]     = y0;
      Bf[bse+M]   = cmul(y1,w1);
      Bf[bse+2*M] = cmul(y2,w2);
      Bf[bse+3*M] = cmul(y3,w3);
    }
    __syncthreads();
  }

  // combine: X[k] = Y0[j] + W^k Y1[j] + W^2k Y2[j],  j = k mod 256 (digit-reversed)
  for (int k = tid; k < N2; k += 64) {
    int j = k & 255;
    int jr = 0, pp = j;
    #pragma unroll
    for (int i = 0; i < 4; ++i) { jr = (jr<<2) | (pp & 3); pp >>= 2; }
    float2 y0 = Bf[jr], y1 = Bf[256 + jr], y2 = Bf[512 + jr];
    float ang = -6.283185307179586f * (float)k / 768.0f;
    float sn, cs; __sincosf(ang, &sn, &cs);
    float2 w  = make_float2(cs, sn);
    float2 w2 = cmul(w, w);
    float rey = y0.x + (w.x*y1.x - w.y*y1.y) + (w2.x*y2.x - w2.y*y2.y);
    pre[k] = rey;                                // out row t1
    if (!special) {
      int km = (k == 0) ? 0 : (N2 - k);
      pim[km] = rey;                             // out row 4096-t1 (mirrored)
    }
  }
}

extern "C" void kernel_launch(void* const* d_in, const int* in_sizes, int n_in,
                              void* d_out, int out_size, void* d_ws, size_t ws_size,
                              hipStream_t stream) {
  const float* x = (const float*)d_in[0];
  float* out = (float*)d_out;
  (void)hipFuncSetAttribute(reinterpret_cast<const void*>(&fft_seq_fused),
                            hipFuncAttributeMaxDynamicSharedMemorySize,
                            4 * CPBUF * (int)sizeof(float2));
  fft_seq_fused<<<dim3(768), dim3(1024), 4 * CPBUF * sizeof(float2), stream>>>(x, out);
  fft_hid_kernel<<<dim3(4098), dim3(256), 0, stream>>>(out);
}

// Round 4
// 171.451 us; speedup vs baseline: 1.2982x; 1.0373x over previous
//
#include <hip/hip_runtime.h>
#include <hip/hip_bf16.h>

#define N1 4096
#define N2 768
#define NCC 384      // complex (paired) columns
#define CG 64        // complex columns per block
#define WS_NEEDED 100663296ull   // 8*64*64*384 complex * 8 B

__device__ __forceinline__ float2 cadd(float2 a, float2 b){ return make_float2(a.x+b.x, a.y+b.y); }
__device__ __forceinline__ float2 csub(float2 a, float2 b){ return make_float2(a.x-b.x, a.y-b.y); }
__device__ __forceinline__ float2 cmul(float2 a, float2 b){ return make_float2(a.x*b.x - a.y*b.y, a.x*b.y + a.y*b.x); }
__device__ __forceinline__ float2 cnegi(float2 a){ return make_float2(a.y, -a.x); }  // -i * a

__device__ __forceinline__ int rev3(int p) {   // reverse 3 base-4 digits (6 bits)
  return ((p & 3) << 4) | (p & 12) | (p >> 4);
}
__device__ __forceinline__ int rev6(int p) {
  int k = 0;
  #pragma unroll
  for (int i = 0; i < 6; ++i) { k = (k << 2) | (p & 3); p >>= 2; }
  return k;
}

// radix-4 DIF butterfly on a column (stride 64 float2 between FFT elements)
__device__ __forceinline__ void bfly64(float2* A, int bb, int M, float fac, int np) {
  float2 a0 = A[bb*64], a1 = A[(bb+M)*64], a2 = A[(bb+2*M)*64], a3 = A[(bb+3*M)*64];
  float2 t0 = cadd(a0,a2), t1 = csub(a0,a2);
  float2 t2 = cadd(a1,a3), t3 = cnegi(csub(a1,a3));
  float2 y0 = cadd(t0,t2), y1 = cadd(t1,t3), y2 = csub(t0,t2), y3 = csub(t1,t3);
  float ang = fac * (float)np;
  float sn, cs; __sincosf(ang, &sn, &cs);
  float2 w1 = make_float2(cs, sn);
  float2 w2 = cmul(w1,w1);
  float2 w3 = cmul(w2,w1);
  A[bb*64]       = y0;
  A[(bb+M)*64]   = cmul(y1,w1);
  A[(bb+2*M)*64] = cmul(y2,w2);
  A[(bb+3*M)*64] = cmul(y3,w3);
}

// P1a: for fixed a, FFT-64 over b of packed complex columns; apply W4096^{a*kb};
// write WS[b8][kb][a][col]. Tile 64(b) x 64(cols) complex = 32 KB.
__global__ __launch_bounds__(256) void p1a_kernel(const float* __restrict__ x,
                                                  float2* __restrict__ ws) {
  __shared__ float2 T[64*64];
  int bid = blockIdx.x;                          // 3072 = 8*384
  int b8  = bid & 7;
  int rem = bid >> 3;                            // 0..383
  int cg  = rem / 64, a = rem % 64;
  const int t = threadIdx.x, l = t & 63, wv = t >> 6;   // 4 waves

  const float* src = x + (size_t)b8 * N1 * N2;
  #pragma unroll 4
  for (int it = 0; it < 16; ++it) {
    int b = wv * 16 + it;
    const float* p = src + (size_t)(a + 64*b) * N2 + 2*(cg*CG + l);
    T[b*64 + l] = *reinterpret_cast<const float2*>(p);
  }
  __syncthreads();

  #pragma unroll
  for (int s = 0; s < 3; ++s) {                  // 64 = 4^3
    int lm = 4 - 2*s;                            // log2 M: 4,2,0
    int M  = 1 << lm;
    float fac = -6.283185307179586f / (float)(1 << (lm+2));
    #pragma unroll
    for (int tt = 0; tt < 4; ++tt) {
      int i   = wv*4 + tt;                       // 0..15
      int np  = i & (M-1);
      int grp = i >> lm;
      int bb  = (grp << (lm+2)) + np;
      bfly64(T + l, bb, M, fac, np);
    }
    __syncthreads();
  }

  float base_ang = -6.283185307179586f / 4096.0f * (float)a;
  #pragma unroll 4
  for (int it = 0; it < 16; ++it) {
    int p  = wv*16 + it;
    int kb = rev3(p);
    float sn, cs; __sincosf(base_ang * (float)kb, &sn, &cs);
    float2 v = cmul(T[p*64 + l], make_float2(cs, sn));
    ws[(((size_t)b8*64 + kb)*64 + a)*NCC + cg*CG + l] = v;
  }
}

// P1b: kb-pair {kb, 64-kb}; FFT-64 over a on both chunks; Hermitian unpack to
// packed d_out rows. 2 tiles x 32 KB = 64 KB dynamic LDS, 512 threads.
__global__ __launch_bounds__(512) void p1b_kernel(const float2* __restrict__ ws,
                                                  float* __restrict__ out) {
  extern __shared__ float2 T[];                  // 2 * 64*64
  int bid = blockIdx.x;                          // 1536 = 8*192
  int b8  = bid & 7;
  int rem = bid >> 3;                            // 0..191
  int cg  = rem / 32, kbt = rem % 32;
  int kb0 = (kbt == 0) ? 0  : kbt;
  int kb1 = (kbt == 0) ? 32 : 64 - kbt;
  const int t = threadIdx.x, l = t & 63, wv = t >> 6;   // 8 waves

  #pragma unroll 4
  for (int it = 0; it < 16; ++it) {
    int ri = wv + 8*it;                          // 0..127
    int ti = ri >> 6, aa = ri & 63;
    int kb = ti ? kb1 : kb0;
    T[ti*4096 + aa*64 + l] =
      ws[(((size_t)b8*64 + kb)*64 + aa)*NCC + cg*CG + l];
  }
  __syncthreads();

  #pragma unroll
  for (int s = 0; s < 3; ++s) {
    int lm = 4 - 2*s;
    int M  = 1 << lm;
    float fac = -6.283185307179586f / (float)(1 << (lm+2));
    #pragma unroll
    for (int tt = 0; tt < 4; ++tt) {
      int i   = (wv >> 1)*4 + tt;                // 0..15
      int ti  = wv & 1;
      int np  = i & (M-1);
      int grp = i >> lm;
      int bb  = (grp << (lm+2)) + np;
      bfly64(T + ti*4096 + l, bb, M, fac, np);
    }
    __syncthreads();
  }

  const size_t obase = (size_t)b8 * N1 * N2;
  #pragma unroll 4
  for (int it = 0; it < 16; ++it) {
    int ri = wv + 8*it;
    int ti = ri >> 6, ka = ri & 63;
    int tj, kap;
    if (kbt == 0) { tj = ti; kap = ti ? (63 - ka) : ((64 - ka) & 63); }
    else          { tj = 1 - ti; kap = 63 - ka; }
    float2 Zk = T[ti*4096 + rev3(ka)*64 + l];
    float2 Zp = T[tj*4096 + rev3(kap)*64 + l];
    int r = (ti ? kb1 : kb0) + 64*ka;
    float2 o;
    if (r <= 2048) o = make_float2(0.5f*(Zk.x + Zp.x), 0.5f*(Zk.y + Zp.y));
    else           o = make_float2(0.5f*(Zp.y - Zk.y), 0.5f*(Zk.x - Zp.x));
    *reinterpret_cast<float2*>(out + obase + (size_t)r * N2 + 2*(cg*CG + l)) = o;
  }
}

// ---------------- fallback path (R3): fused pass 1, no workspace ----------------
#define PADI(i) ((i) + ((i) >> 4))
#define CPBUF 4352

__device__ __forceinline__ void bfly4p(float2* arr, int base, int M, float fac, int np) {
  float2 a0 = arr[PADI(base)], a1 = arr[PADI(base+M)];
  float2 a2 = arr[PADI(base+2*M)], a3 = arr[PADI(base+3*M)];
  float2 t0 = cadd(a0,a2), t1 = csub(a0,a2);
  float2 t2 = cadd(a1,a3), t3 = cnegi(csub(a1,a3));
  float2 y0 = cadd(t0,t2), y1 = cadd(t1,t3), y2 = csub(t0,t2), y3 = csub(t1,t3);
  float ang = fac * (float)np;
  float sn, cs; __sincosf(ang, &sn, &cs);
  float2 w1 = make_float2(cs, sn);
  float2 w2 = cmul(w1,w1);
  float2 w3 = cmul(w2,w1);
  arr[PADI(base)]     = y0;
  arr[PADI(base+M)]   = cmul(y1,w1);
  arr[PADI(base+2*M)] = cmul(y2,w2);
  arr[PADI(base+3*M)] = cmul(y3,w3);
}

__global__ __launch_bounds__(1024) void fft_seq_fused(const float* __restrict__ x,
                                                      float* __restrict__ out) {
  extern __shared__ float2 lds[];
  int bid = blockIdx.x;
  int wg  = (bid & 7) * 96 + (bid >> 3);
  int b   = wg / 96;
  int g   = wg % 96;
  const int t = threadIdx.x;
  const size_t base = (size_t)b * N1 * N2 + 8 * (size_t)g;

  for (int r = t; r < N1; r += 1024) {
    const float* p = x + base + (size_t)r * N2;
    float4 A  = *reinterpret_cast<const float4*>(p);
    float4 Bv = *reinterpret_cast<const float4*>(p + 4);
    int ip = PADI(r);
    lds[ip]             = make_float2(A.x, A.y);
    lds[CPBUF + ip]     = make_float2(A.z, A.w);
    lds[2*CPBUF + ip]   = make_float2(Bv.x, Bv.y);
    lds[3*CPBUF + ip]   = make_float2(Bv.z, Bv.w);
  }
  __syncthreads();

  const int wv  = t >> 6;
  const int cp  = wv & 3;
  const int idx = ((wv >> 2) << 6) + (t & 63);
  float2* buf = lds + cp * CPBUF;

  #pragma unroll
  for (int s = 0; s < 6; ++s) {
    int lm = 10 - 2*s;
    int M  = 1 << lm;
    float fac = -6.283185307179586f / (float)(4*M);
    #pragma unroll
    for (int jj = 0; jj < 4; ++jj) {
      int j   = idx + (jj << 8);
      int np  = j & (M-1);
      int grp = j >> lm;
      int bse = (grp << (lm+2)) + np;
      bfly4p(buf, bse, M, fac, np);
    }
    __syncthreads();
  }

  float* orow = out + base;
  #pragma unroll
  for (int i = 0; i < 4; ++i) {
    int k  = ((t & 63) << 6) + (t >> 6) + (i << 4);
    int km = (N1 - k) & (N1 - 1);
    int pk = PADI(rev6(k));
    int pn = PADI(rev6(km));
    float o[8];
    #pragma unroll
    for (int c = 0; c < 4; ++c) {
      float2 zk = lds[c*CPBUF + pk];
      float2 zn = lds[c*CPBUF + pn];
      if (k <= 2048) { o[2*c] = 0.5f*(zk.x + zn.x); o[2*c+1] = 0.5f*(zk.y + zn.y); }
      else           { o[2*c] = 0.5f*(zn.y - zk.y); o[2*c+1] = 0.5f*(zk.x - zn.x); }
    }
    float* q = orow + (size_t)k * N2;
    *reinterpret_cast<float4*>(q)     = make_float4(o[0], o[1], o[2], o[3]);
    *reinterpret_cast<float4*>(q + 4) = make_float4(o[4], o[5], o[6], o[7]);
  }
}

// Pass 2: 768-pt FFT along hidden axis, one task per conjugate row pair.
__global__ __launch_bounds__(256) void fft_hid_kernel(float* __restrict__ out) {
  __shared__ float2 buf[4][768];
  const int grp = threadIdx.x >> 6;
  const int tid = threadIdx.x & 63;
  int task = blockIdx.x * 4 + grp;
  int b  = task / 2049;
  int t1 = task - b * 2049;
  const bool special = (t1 == 0) || (t1 == 2048);
  float* baseB = out + (size_t)b * N1 * N2;
  float* pre = baseB + (size_t)t1 * N2;
  float* pim = baseB + (size_t)(N1 - t1) * N2;
  float2* Bf = buf[grp];

  for (int n = tid; n < N2; n += 64) {
    int np = n / 3;
    int q  = n - 3*np;
    float re = pre[n];
    float im = special ? 0.0f : pim[n];
    Bf[q*256 + np] = make_float2(re, im);
  }
  __syncthreads();

  #pragma unroll
  for (int s = 0; s < 4; ++s) {
    int lm = 6 - 2*s;
    int M  = 1 << lm;
    float fac = -6.283185307179586f / (float)(4*M);
    for (int j = tid; j < 192; j += 64) {
      int sub = j >> 6;
      int jj  = j & 63;
      int np  = jj & (M-1);
      int gi  = jj >> lm;
      int bse = sub*256 + (gi << (lm+2)) + np;
      float2 a0 = Bf[bse], a1 = Bf[bse+M], a2 = Bf[bse+2*M], a3 = Bf[bse+3*M];
      float2 t0 = cadd(a0,a2), t1v = csub(a0,a2);
      float2 t2 = cadd(a1,a3), t3 = cnegi(csub(a1,a3));
      float2 y0 = cadd(t0,t2), y1 = cadd(t1v,t3), y2 = csub(t0,t2), y3 = csub(t1v,t3);
      float ang = fac * (float)np;
      float sn, cs; __sincosf(ang, &sn, &cs);
      float2 w1 = make_float2(cs, sn);
      float2 w2 = cmul(w1,w1);
      float2 w3 = cmul(w2,w1);
      Bf[bse]     = y0;
      Bf[bse+M]   = cmul(y1,w1);
      Bf[bse+2*M] = cmul(y2,w2);
      Bf[bse+3*M] = cmul(y3,w3);
    }
    __syncthreads();
  }

  for (int k = tid; k < N2; k += 64) {
    int j = k & 255;
    int jr = 0, pp = j;
    #pragma unroll
    for (int i = 0; i < 4; ++i) { jr = (jr<<2) | (pp & 3); pp >>= 2; }
    float2 y0 = Bf[jr], y1 = Bf[256 + jr], y2 = Bf[512 + jr];
    float ang = -6.283185307179586f * (float)k / 768.0f;
    float sn, cs; __sincosf(ang, &sn, &cs);
    float2 w  = make_float2(cs, sn);
    float2 w2 = cmul(w, w);
    float rey = y0.x + (w.x*y1.x - w.y*y1.y) + (w2.x*y2.x - w2.y*y2.y);
    pre[k] = rey;
    if (!special) {
      int km = (k == 0) ? 0 : (N2 - k);
      pim[km] = rey;
    }
  }
}

extern "C" void kernel_launch(void* const* d_in, const int* in_sizes, int n_in,
                              void* d_out, int out_size, void* d_ws, size_t ws_size,
                              hipStream_t stream) {
  const float* x = (const float*)d_in[0];
  float* out = (float*)d_out;
  if (ws_size >= WS_NEEDED) {
    float2* ws = (float2*)d_ws;
    p1a_kernel<<<dim3(3072), dim3(256), 0, stream>>>(x, ws);
    p1b_kernel<<<dim3(1536), dim3(512), 65536, stream>>>(ws, out);
  } else {
    (void)hipFuncSetAttribute(reinterpret_cast<const void*>(&fft_seq_fused),
                              hipFuncAttributeMaxDynamicSharedMemorySize,
                              4 * CPBUF * (int)sizeof(float2));
    fft_seq_fused<<<dim3(768), dim3(1024), 4 * CPBUF * sizeof(float2), stream>>>(x, out);
  }
  fft_hid_kernel<<<dim3(4098), dim3(256), 0, stream>>>(out);
}

// Round 5
// 123.829 us; speedup vs baseline: 1.7974x; 1.3846x over previous
//
#include <hip/hip_runtime.h>
#include <hip/hip_bf16.h>

#define N1 4096
#define N2 768
#define NCC 384      // complex (paired) columns
#define CG 64        // complex columns per block
#define WS_NEEDED 100663296ull   // 8*64*64*384 complex * 8 B

__device__ __forceinline__ float2 cadd(float2 a, float2 b){ return make_float2(a.x+b.x, a.y+b.y); }
__device__ __forceinline__ float2 csub(float2 a, float2 b){ return make_float2(a.x-b.x, a.y-b.y); }
__device__ __forceinline__ float2 cmul(float2 a, float2 b){ return make_float2(a.x*b.x - a.y*b.y, a.x*b.y + a.y*b.x); }
__device__ __forceinline__ float2 cnegi(float2 a){ return make_float2(a.y, -a.x); }  // -i * a

__device__ __forceinline__ int rev3(int p) {   // reverse 3 base-4 digits (6 bits)
  return ((p & 3) << 4) | (p & 12) | (p >> 4);
}
__device__ __forceinline__ int rev6(int p) {
  int k = 0;
  #pragma unroll
  for (int i = 0; i < 6; ++i) { k = (k << 2) | (p & 3); p >>= 2; }
  return k;
}

// radix-4 DIF butterfly on a column (stride 64 float2 between FFT elements)
__device__ __forceinline__ void bfly64(float2* A, int bb, int M, float fac, int np) {
  float2 a0 = A[bb*64], a1 = A[(bb+M)*64], a2 = A[(bb+2*M)*64], a3 = A[(bb+3*M)*64];
  float2 t0 = cadd(a0,a2), t1 = csub(a0,a2);
  float2 t2 = cadd(a1,a3), t3 = cnegi(csub(a1,a3));
  float2 y0 = cadd(t0,t2), y1 = cadd(t1,t3), y2 = csub(t0,t2), y3 = csub(t1,t3);
  float ang = fac * (float)np;
  float sn, cs; __sincosf(ang, &sn, &cs);
  float2 w1 = make_float2(cs, sn);
  float2 w2 = cmul(w1,w1);
  float2 w3 = cmul(w2,w1);
  A[bb*64]       = y0;
  A[(bb+M)*64]   = cmul(y1,w1);
  A[(bb+2*M)*64] = cmul(y2,w2);
  A[(bb+3*M)*64] = cmul(y3,w3);
}

// P1a: for fixed a, FFT-64 over b of packed complex columns; apply W4096^{a*kb};
// write WS[b8][kb][a][col]. Tile 64(b) x 64(cols) complex = 32 KB.
__global__ __launch_bounds__(256) void p1a_kernel(const float* __restrict__ x,
                                                  float2* __restrict__ ws) {
  __shared__ float2 T[64*64];
  int bid = blockIdx.x;                          // 3072 = 8*384
  int b8  = bid & 7;
  int rem = bid >> 3;                            // 0..383
  int cg  = rem / 64, a = rem % 64;
  const int t = threadIdx.x, l = t & 63, wv = t >> 6;   // 4 waves

  const float* src = x + (size_t)b8 * N1 * N2;
  #pragma unroll 4
  for (int it = 0; it < 16; ++it) {
    int b = wv * 16 + it;
    const float* p = src + (size_t)(a + 64*b) * N2 + 2*(cg*CG + l);
    T[b*64 + l] = *reinterpret_cast<const float2*>(p);
  }
  __syncthreads();

  #pragma unroll
  for (int s = 0; s < 3; ++s) {                  // 64 = 4^3
    int lm = 4 - 2*s;                            // log2 M: 4,2,0
    int M  = 1 << lm;
    float fac = -6.283185307179586f / (float)(1 << (lm+2));
    #pragma unroll
    for (int tt = 0; tt < 4; ++tt) {
      int i   = wv*4 + tt;                       // 0..15
      int np  = i & (M-1);
      int grp = i >> lm;
      int bb  = (grp << (lm+2)) + np;
      bfly64(T + l, bb, M, fac, np);
    }
    __syncthreads();
  }

  float base_ang = -6.283185307179586f / 4096.0f * (float)a;
  #pragma unroll 4
  for (int it = 0; it < 16; ++it) {
    int p  = wv*16 + it;
    int kb = rev3(p);
    float sn, cs; __sincosf(base_ang * (float)kb, &sn, &cs);
    float2 v = cmul(T[p*64 + l], make_float2(cs, sn));
    ws[(((size_t)b8*64 + kb)*64 + a)*NCC + cg*CG + l] = v;
  }
}

// P1b: kb-pair {kb, 64-kb}; FFT-64 over a on both chunks; Hermitian unpack to
// packed d_out rows. 2 tiles x 32 KB = 64 KB dynamic LDS, 512 threads.
__global__ __launch_bounds__(512) void p1b_kernel(const float2* __restrict__ ws,
                                                  float* __restrict__ out) {
  extern __shared__ float2 T[];                  // 2 * 64*64
  int bid = blockIdx.x;                          // 1536 = 8*192
  int b8  = bid & 7;
  int rem = bid >> 3;                            // 0..191
  int cg  = rem / 32, kbt = rem % 32;
  int kb0 = (kbt == 0) ? 0  : kbt;
  int kb1 = (kbt == 0) ? 32 : 64 - kbt;
  const int t = threadIdx.x, l = t & 63, wv = t >> 6;   // 8 waves

  #pragma unroll 4
  for (int it = 0; it < 16; ++it) {
    int ri = wv + 8*it;                          // 0..127
    int ti = ri >> 6, aa = ri & 63;
    int kb = ti ? kb1 : kb0;
    T[ti*4096 + aa*64 + l] =
      ws[(((size_t)b8*64 + kb)*64 + aa)*NCC + cg*CG + l];
  }
  __syncthreads();

  #pragma unroll
  for (int s = 0; s < 3; ++s) {
    int lm = 4 - 2*s;
    int M  = 1 << lm;
    float fac = -6.283185307179586f / (float)(1 << (lm+2));
    #pragma unroll
    for (int tt = 0; tt < 4; ++tt) {
      int i   = (wv >> 1)*4 + tt;                // 0..15
      int ti  = wv & 1;
      int np  = i & (M-1);
      int grp = i >> lm;
      int bb  = (grp << (lm+2)) + np;
      bfly64(T + ti*4096 + l, bb, M, fac, np);
    }
    __syncthreads();
  }

  const size_t obase = (size_t)b8 * N1 * N2;
  #pragma unroll 4
  for (int it = 0; it < 16; ++it) {
    int ri = wv + 8*it;
    int ti = ri >> 6, ka = ri & 63;
    int tj, kap;
    if (kbt == 0) { tj = ti; kap = ti ? (63 - ka) : ((64 - ka) & 63); }
    else          { tj = 1 - ti; kap = 63 - ka; }
    float2 Zk = T[ti*4096 + rev3(ka)*64 + l];
    float2 Zp = T[tj*4096 + rev3(kap)*64 + l];
    int r = (ti ? kb1 : kb0) + 64*ka;
    float2 o;
    if (r <= 2048) o = make_float2(0.5f*(Zk.x + Zp.x), 0.5f*(Zk.y + Zp.y));
    else           o = make_float2(0.5f*(Zp.y - Zk.y), 0.5f*(Zk.x - Zp.x));
    *reinterpret_cast<float2*>(out + obase + (size_t)r * N2 + 2*(cg*CG + l)) = o;
  }
}

// ---------------- fallback path (R3): fused pass 1, no workspace ----------------
#define PADI(i) ((i) + ((i) >> 4))
#define CPBUF 4352

__device__ __forceinline__ void bfly4p(float2* arr, int base, int M, float fac, int np) {
  float2 a0 = arr[PADI(base)], a1 = arr[PADI(base+M)];
  float2 a2 = arr[PADI(base+2*M)], a3 = arr[PADI(base+3*M)];
  float2 t0 = cadd(a0,a2), t1 = csub(a0,a2);
  float2 t2 = cadd(a1,a3), t3 = cnegi(csub(a1,a3));
  float2 y0 = cadd(t0,t2), y1 = cadd(t1,t3), y2 = csub(t0,t2), y3 = csub(t1,t3);
  float ang = fac * (float)np;
  float sn, cs; __sincosf(ang, &sn, &cs);
  float2 w1 = make_float2(cs, sn);
  float2 w2 = cmul(w1,w1);
  float2 w3 = cmul(w2,w1);
  arr[PADI(base)]     = y0;
  arr[PADI(base+M)]   = cmul(y1,w1);
  arr[PADI(base+2*M)] = cmul(y2,w2);
  arr[PADI(base+3*M)] = cmul(y3,w3);
}

__global__ __launch_bounds__(1024) void fft_seq_fused(const float* __restrict__ x,
                                                      float* __restrict__ out) {
  extern __shared__ float2 lds[];
  int bid = blockIdx.x;
  int wg  = (bid & 7) * 96 + (bid >> 3);
  int b   = wg / 96;
  int g   = wg % 96;
  const int t = threadIdx.x;
  const size_t base = (size_t)b * N1 * N2 + 8 * (size_t)g;

  for (int r = t; r < N1; r += 1024) {
    const float* p = x + base + (size_t)r * N2;
    float4 A  = *reinterpret_cast<const float4*>(p);
    float4 Bv = *reinterpret_cast<const float4*>(p + 4);
    int ip = PADI(r);
    lds[ip]             = make_float2(A.x, A.y);
    lds[CPBUF + ip]     = make_float2(A.z, A.w);
    lds[2*CPBUF + ip]   = make_float2(Bv.x, Bv.y);
    lds[3*CPBUF + ip]   = make_float2(Bv.z, Bv.w);
  }
  __syncthreads();

  const int wv  = t >> 6;
  const int cp  = wv & 3;
  const int idx = ((wv >> 2) << 6) + (t & 63);
  float2* buf = lds + cp * CPBUF;

  #pragma unroll
  for (int s = 0; s < 6; ++s) {
    int lm = 10 - 2*s;
    int M  = 1 << lm;
    float fac = -6.283185307179586f / (float)(4*M);
    #pragma unroll
    for (int jj = 0; jj < 4; ++jj) {
      int j   = idx + (jj << 8);
      int np  = j & (M-1);
      int grp = j >> lm;
      int bse = (grp << (lm+2)) + np;
      bfly4p(buf, bse, M, fac, np);
    }
    __syncthreads();
  }

  float* orow = out + base;
  #pragma unroll
  for (int i = 0; i < 4; ++i) {
    int k  = ((t & 63) << 6) + (t >> 6) + (i << 4);
    int km = (N1 - k) & (N1 - 1);
    int pk = PADI(rev6(k));
    int pn = PADI(rev6(km));
    float o[8];
    #pragma unroll
    for (int c = 0; c < 4; ++c) {
      float2 zk = lds[c*CPBUF + pk];
      float2 zn = lds[c*CPBUF + pn];
      if (k <= 2048) { o[2*c] = 0.5f*(zk.x + zn.x); o[2*c+1] = 0.5f*(zk.y + zn.y); }
      else           { o[2*c] = 0.5f*(zn.y - zk.y); o[2*c+1] = 0.5f*(zk.x - zn.x); }
    }
    float* q = orow + (size_t)k * N2;
    *reinterpret_cast<float4*>(q)     = make_float4(o[0], o[1], o[2], o[3]);
    *reinterpret_cast<float4*>(q + 4) = make_float4(o[4], o[5], o[6], o[7]);
  }
}

// Pass 2: 768-pt FFT along hidden axis, one WAVE per conjugate row pair.
// 768 = 64(lanes) x 12(registers). In-lane FFT-12 (const twiddles) ->
// W768^{l*km} twiddle -> cross-lane FFT-64 via 6 radix-2 shfl_xor stages
// (zero LDS) -> small LDS transpose (Re only) -> coalesced stores.
__global__ __launch_bounds__(256) void fft_hid_kernel(float* __restrict__ out) {
  __shared__ float T[4][12*69];                 // stride 69: conflict-light
  const int grp = threadIdx.x >> 6;
  const int l   = threadIdx.x & 63;
  int task = blockIdx.x * 4 + grp;              // 16392 = 4098*4 exact
  int b  = task / 2049;
  int t1 = task - b * 2049;                     // 0..2048
  const bool special = (t1 == 0) || (t1 == 2048);
  float* baseB = out + (size_t)b * N1 * N2;
  float* pre = baseB + (size_t)t1 * N2;         // Re X[t1]
  float* pim = baseB + (size_t)(N1 - t1) * N2;  // Im X[t1] (packed row)

  // load: z[m] = value at n = l + 64m (coalesced 256B per instr)
  float2 z[12];
  #pragma unroll
  for (int m = 0; m < 12; ++m) {
    float re = pre[(m << 6) + l];
    float im = special ? 0.0f : pim[(m << 6) + l];
    z[m] = make_float2(re, im);
  }

  // in-lane FFT-12: b = 3p+q; 3 x FFT-4 over p, const twiddles, 4 x FFT-3 over q
  float2 A[3][4];
  #pragma unroll
  for (int q = 0; q < 3; ++q) {
    float2 s0 = z[q], s1 = z[3+q], s2 = z[6+q], s3 = z[9+q];
    float2 t0 = cadd(s0,s2), t1v = csub(s0,s2);
    float2 t2 = cadd(s1,s3), t3 = cnegi(csub(s1,s3));
    A[q][0] = cadd(t0,t2); A[q][1] = cadd(t1v,t3);
    A[q][2] = csub(t0,t2); A[q][3] = csub(t1v,t3);
  }
  const float h3 = 0.8660254037844386f;
  const float2 W1[4] = { {1.f,0.f}, {h3,-0.5f}, {0.5f,-h3}, {0.f,-1.f} };   // w12^k4
  const float2 W2[4] = { {1.f,0.f}, {0.5f,-h3}, {-0.5f,-h3}, {-1.f,0.f} };  // w12^2k4
  float2 y[12];
  #pragma unroll
  for (int k4 = 0; k4 < 4; ++k4) {
    float2 C0 = A[0][k4];
    float2 C1 = cmul(A[1][k4], W1[k4]);
    float2 C2 = cmul(A[2][k4], W2[k4]);
    float2 tt = cadd(C1,C2), d = csub(C1,C2);
    float2 u  = make_float2(C0.x - 0.5f*tt.x, C0.y - 0.5f*tt.y);
    float2 idd = make_float2(h3*d.y, -h3*d.x);  // i*(-h3)*d
    y[k4]   = cadd(C0, tt);
    y[k4+4] = cadd(u, idd);
    y[k4+8] = csub(u, idd);
  }

  // twiddle W768^{l*km}
  float base = -6.283185307179586f * (float)l / 768.0f;
  #pragma unroll
  for (int km = 1; km < 12; ++km) {
    float sn, cs; __sincosf(base * (float)km, &sn, &cs);
    y[km] = cmul(y[km], make_float2(cs, sn));
  }

  // cross-lane FFT-64: radix-2 DIF, 6 stages, register-only
  #pragma unroll
  for (int st = 0; st < 6; ++st) {
    int h = 32 >> st;
    int j = l & (h - 1);
    float sn, cs; __sincosf(-3.14159265358979f * (float)j / (float)h, &sn, &cs);
    float2 w = make_float2(cs, sn);
    bool hi = (l & h) != 0;
    #pragma unroll
    for (int m = 0; m < 12; ++m) {
      float px = __shfl_xor(y[m].x, h, 64);
      float py = __shfl_xor(y[m].y, h, 64);
      float2 p = make_float2(px, py);
      float2 lo  = cadd(y[m], p);
      float2 hiv = cmul(csub(p, y[m]), w);
      y[m] = hi ? hiv : lo;
    }
  }

  // lane p holds X[km + 12*rev6bit(p)]; transpose Re via LDS, store coalesced
  int r = ((l&1)<<5)|((l&2)<<3)|((l&4)<<1)|((l&8)>>1)|((l&16)>>3)|((l&32)>>5);
  float* Tb = T[grp];
  #pragma unroll
  for (int km = 0; km < 12; ++km) Tb[km*69 + r] = y[km].x;
  __syncthreads();

  #pragma unroll
  for (int mp = 0; mp < 12; ++mp) {
    int k = (mp << 6) + l;
    float v = Tb[(k % 12)*69 + (k / 12)];
    pre[k] = v;
    if (!special) pim[(N2 - k) % N2] = v;
  }
}

extern "C" void kernel_launch(void* const* d_in, const int* in_sizes, int n_in,
                              void* d_out, int out_size, void* d_ws, size_t ws_size,
                              hipStream_t stream) {
  const float* x = (const float*)d_in[0];
  float* out = (float*)d_out;
  if (ws_size >= WS_NEEDED) {
    float2* ws = (float2*)d_ws;
    p1a_kernel<<<dim3(3072), dim3(256), 0, stream>>>(x, ws);
    p1b_kernel<<<dim3(1536), dim3(512), 65536, stream>>>(ws, out);
  } else {
    (void)hipFuncSetAttribute(reinterpret_cast<const void*>(&fft_seq_fused),
                              hipFuncAttributeMaxDynamicSharedMemorySize,
                              4 * CPBUF * (int)sizeof(float2));
    fft_seq_fused<<<dim3(768), dim3(1024), 4 * CPBUF * sizeof(float2), stream>>>(x, out);
  }
  fft_hid_kernel<<<dim3(4098), dim3(256), 0, stream>>>(out);
}

// Round 6
// 108.745 us; speedup vs baseline: 2.0467x; 1.1387x over previous
//
#include <hip/hip_runtime.h>
#include <hip/hip_bf16.h>

#define N1 4096
#define N2 768
#define NCC 384      // complex (paired real) columns
#define CG 64        // complex columns per block
#define WS_NEEDED 100663296ull   // 8*64*64*384 complex * 8 B

__device__ __forceinline__ float2 cadd(float2 a, float2 b){ return make_float2(a.x+b.x, a.y+b.y); }
__device__ __forceinline__ float2 csub(float2 a, float2 b){ return make_float2(a.x-b.x, a.y-b.y); }
__device__ __forceinline__ float2 cmul(float2 a, float2 b){ return make_float2(a.x*b.x - a.y*b.y, a.x*b.y + a.y*b.x); }
__device__ __forceinline__ float2 cnegi(float2 a){ return make_float2(a.y, -a.x); }  // -i * a

__device__ __forceinline__ int rev6(int p) {
  int k = 0;
  #pragma unroll
  for (int i = 0; i < 6; ++i) { k = (k << 2) | (p & 3); p >>= 2; }
  return k;
}

// In-register DIF FFT-8, natural-order outputs. X[k] = sum_j z[j] W8^{jk}.
__device__ __forceinline__ void fft8(float2 z[8]) {
  const float RH = 0.70710678118654752f;
  float2 u0=cadd(z[0],z[4]), v0=csub(z[0],z[4]);
  float2 u1=cadd(z[1],z[5]), v1=csub(z[1],z[5]);
  float2 u2=cadd(z[2],z[6]), v2=csub(z[2],z[6]);
  float2 u3=cadd(z[3],z[7]), v3=csub(z[3],z[7]);
  // v1 *= W8^1=(1-i)RH ; v2 *= W8^2=-i ; v3 *= W8^3=-(1+i)RH
  v1 = make_float2(RH*(v1.x+v1.y), RH*(v1.y-v1.x));
  v2 = cnegi(v2);
  v3 = make_float2(RH*(v3.y-v3.x), -RH*(v3.x+v3.y));
  float2 a0=cadd(u0,u2), b0=csub(u0,u2);
  float2 a1=cadd(u1,u3), b1=cnegi(csub(u1,u3));
  float2 c0=cadd(v0,v2), d0=csub(v0,v2);
  float2 c1=cadd(v1,v3), d1=cnegi(csub(v1,v3));
  z[0]=cadd(a0,a1); z[4]=csub(a0,a1);
  z[2]=cadd(b0,b1); z[6]=csub(b0,b1);
  z[1]=cadd(c0,c1); z[5]=csub(c0,c1);
  z[3]=cadd(d0,d1); z[7]=csub(d0,d1);
}

// P1a: FFT-64 over b (rows a+64b) of packed complex columns, * W4096^{a*kb}.
// 8-in-reg x LDS-transpose x 8-in-reg; ONE barrier. 512 thr, 32 KB LDS.
__global__ __launch_bounds__(512) void p1a_kernel(const float* __restrict__ x,
                                                  float2* __restrict__ ws) {
  __shared__ float2 T[4096];                     // [ (k0*8+b0)*64 + c ]
  int bid = blockIdx.x;                          // 3072 = 8*384
  int b8  = bid & 7;
  int rem = bid >> 3;
  int cg  = rem / 64, a = rem % 64;
  const int t = threadIdx.x, l = t & 63, wv = t >> 6;   // wv = b0

  const float* src = x + (size_t)b8 * N1 * N2 + 2*(cg*CG + l);
  float2 z[8];
  #pragma unroll
  for (int b1 = 0; b1 < 8; ++b1) {
    int row = a + 64*(8*b1 + wv);
    z[b1] = *reinterpret_cast<const float2*>(src + (size_t)row * N2);
  }
  fft8(z);                                       // z[k0] = Y_{b0}[k0]
  float fac = -6.283185307179586f/64.0f * (float)wv;
  #pragma unroll
  for (int k0 = 1; k0 < 8; ++k0) {
    float sn, cs; __sincosf(fac * (float)k0, &sn, &cs);
    z[k0] = cmul(z[k0], make_float2(cs, sn));
  }
  #pragma unroll
  for (int k0 = 0; k0 < 8; ++k0) T[(k0*8 + wv)*64 + l] = z[k0];
  __syncthreads();
  #pragma unroll
  for (int b0 = 0; b0 < 8; ++b0) z[b0] = T[(wv*8 + b0)*64 + l];
  fft8(z);                                       // z[k1] = X[8k1 + wv]
  float fa = -6.283185307179586f/4096.0f * (float)a;
  #pragma unroll
  for (int k1 = 0; k1 < 8; ++k1) {
    int kb = 8*k1 + wv;
    float sn, cs; __sincosf(fa * (float)kb, &sn, &cs);
    float2 v = cmul(z[k1], make_float2(cs, sn));
    ws[(((size_t)b8*64 + kb)*64 + a)*NCC + cg*CG + l] = v;
  }
}

// P1b: FFT-64 over a for kb-pair {kb, 64-kb}; Hermitian unpack to packed out.
// Same reg/transpose structure; 1024 thr, 64 KB LDS, 3 barriers.
__global__ __launch_bounds__(1024) void p1b_kernel(const float2* __restrict__ ws,
                                                   float* __restrict__ out) {
  __shared__ float2 T[2][4096];
  int bid = blockIdx.x;                          // 1536 = 8*192
  int b8  = bid & 7;
  int rem = bid >> 3;
  int cg  = rem / 32, kbt = rem % 32;
  int kb0 = (kbt == 0) ? 0  : kbt;
  int kb1 = (kbt == 0) ? 32 : 64 - kbt;
  const int t = threadIdx.x, l = t & 63, wv = (t >> 6) & 7, ti = t >> 9;
  const int kb = ti ? kb1 : kb0;

  const float2* wsrc = ws + (((size_t)b8*64 + kb)*64)*NCC + cg*CG + l;
  float2 z[8];
  #pragma unroll
  for (int a1 = 0; a1 < 8; ++a1)
    z[a1] = wsrc[(size_t)(8*a1 + wv) * NCC];
  fft8(z);                                       // z[q]=Y_{a0=wv}[q]
  float fac = -6.283185307179586f/64.0f * (float)wv;
  #pragma unroll
  for (int q = 1; q < 8; ++q) {
    float sn, cs; __sincosf(fac * (float)q, &sn, &cs);
    z[q] = cmul(z[q], make_float2(cs, sn));
  }
  #pragma unroll
  for (int q = 0; q < 8; ++q) T[ti][(q*8 + wv)*64 + l] = z[q];
  __syncthreads();
  #pragma unroll
  for (int a0 = 0; a0 < 8; ++a0) z[a0] = T[ti][(wv*8 + a0)*64 + l];
  fft8(z);                                       // z[ka1] = Z_kb[8ka1 + wv]
  __syncthreads();
  #pragma unroll
  for (int ka1 = 0; ka1 < 8; ++ka1) T[ti][(8*ka1 + wv)*64 + l] = z[ka1];  // natural ka
  __syncthreads();

  const size_t obase = (size_t)b8 * N1 * N2;
  #pragma unroll
  for (int it = 0; it < 8; ++it) {
    int ka = 8*it + wv;
    int tj, kap;
    if (kbt == 0) { tj = ti; kap = ti ? (63 - ka) : ((64 - ka) & 63); }
    else          { tj = 1 - ti; kap = 63 - ka; }
    float2 Zk = T[ti][ka*64 + l];
    float2 Zp = T[tj][kap*64 + l];
    int r = kb + 64*ka;
    float2 o;
    if (r <= 2048) o = make_float2(0.5f*(Zk.x + Zp.x), 0.5f*(Zk.y + Zp.y));
    else           o = make_float2(0.5f*(Zp.y - Zk.y), 0.5f*(Zk.x - Zp.x));
    *reinterpret_cast<float2*>(out + obase + (size_t)r * N2 + 2*(cg*CG + l)) = o;
  }
}

// ---------------- fallback path (no workspace): R3 fused pass 1 ----------------
#define PADI(i) ((i) + ((i) >> 4))
#define CPBUF 4352

__device__ __forceinline__ void bfly4p(float2* arr, int base, int M, float fac, int np) {
  float2 a0 = arr[PADI(base)], a1 = arr[PADI(base+M)];
  float2 a2 = arr[PADI(base+2*M)], a3 = arr[PADI(base+3*M)];
  float2 t0 = cadd(a0,a2), t1 = csub(a0,a2);
  float2 t2 = cadd(a1,a3), t3 = cnegi(csub(a1,a3));
  float2 y0 = cadd(t0,t2), y1 = cadd(t1,t3), y2 = csub(t0,t2), y3 = csub(t1,t3);
  float ang = fac * (float)np;
  float sn, cs; __sincosf(ang, &sn, &cs);
  float2 w1 = make_float2(cs, sn);
  float2 w2 = cmul(w1,w1);
  float2 w3 = cmul(w2,w1);
  arr[PADI(base)]     = y0;
  arr[PADI(base+M)]   = cmul(y1,w1);
  arr[PADI(base+2*M)] = cmul(y2,w2);
  arr[PADI(base+3*M)] = cmul(y3,w3);
}

__global__ __launch_bounds__(1024) void fft_seq_fused(const float* __restrict__ x,
                                                      float* __restrict__ out) {
  extern __shared__ float2 lds[];
  int bid = blockIdx.x;
  int wg  = (bid & 7) * 96 + (bid >> 3);
  int b   = wg / 96;
  int g   = wg % 96;
  const int t = threadIdx.x;
  const size_t base = (size_t)b * N1 * N2 + 8 * (size_t)g;

  for (int r = t; r < N1; r += 1024) {
    const float* p = x + base + (size_t)r * N2;
    float4 A  = *reinterpret_cast<const float4*>(p);
    float4 Bv = *reinterpret_cast<const float4*>(p + 4);
    int ip = PADI(r);
    lds[ip]             = make_float2(A.x, A.y);
    lds[CPBUF + ip]     = make_float2(A.z, A.w);
    lds[2*CPBUF + ip]   = make_float2(Bv.x, Bv.y);
    lds[3*CPBUF + ip]   = make_float2(Bv.z, Bv.w);
  }
  __syncthreads();

  const int wv  = t >> 6;
  const int cp  = wv & 3;
  const int idx = ((wv >> 2) << 6) + (t & 63);
  float2* buf = lds + cp * CPBUF;

  #pragma unroll
  for (int s = 0; s < 6; ++s) {
    int lm = 10 - 2*s;
    int M  = 1 << lm;
    float fac = -6.283185307179586f / (float)(4*M);
    #pragma unroll
    for (int jj = 0; jj < 4; ++jj) {
      int j   = idx + (jj << 8);
      int np  = j & (M-1);
      int grp = j >> lm;
      int bse = (grp << (lm+2)) + np;
      bfly4p(buf, bse, M, fac, np);
    }
    __syncthreads();
  }

  float* orow = out + base;
  #pragma unroll
  for (int i = 0; i < 4; ++i) {
    int k  = ((t & 63) << 6) + (t >> 6) + (i << 4);
    int km = (N1 - k) & (N1 - 1);
    int pk = PADI(rev6(k));
    int pn = PADI(rev6(km));
    float o[8];
    #pragma unroll
    for (int c = 0; c < 4; ++c) {
      float2 zk = lds[c*CPBUF + pk];
      float2 zn = lds[c*CPBUF + pn];
      if (k <= 2048) { o[2*c] = 0.5f*(zk.x + zn.x); o[2*c+1] = 0.5f*(zk.y + zn.y); }
      else           { o[2*c] = 0.5f*(zn.y - zk.y); o[2*c+1] = 0.5f*(zk.x - zn.x); }
    }
    float* q = orow + (size_t)k * N2;
    *reinterpret_cast<float4*>(q)     = make_float4(o[0], o[1], o[2], o[3]);
    *reinterpret_cast<float4*>(q + 4) = make_float4(o[4], o[5], o[6], o[7]);
  }
}

// Pass 2: 768-pt FFT along hidden axis, one WAVE per conjugate row pair.
// 768 = 64(lanes) x 12(registers); shfl-based cross-lane FFT-64.
__global__ __launch_bounds__(256) void fft_hid_kernel(float* __restrict__ out) {
  __shared__ float T[4][12*69];
  const int grp = threadIdx.x >> 6;
  const int l   = threadIdx.x & 63;
  int task = blockIdx.x * 4 + grp;              // 16392 = 4098*4 exact
  int b  = task / 2049;
  int t1 = task - b * 2049;                     // 0..2048
  const bool special = (t1 == 0) || (t1 == 2048);
  float* baseB = out + (size_t)b * N1 * N2;
  float* pre = baseB + (size_t)t1 * N2;
  float* pim = baseB + (size_t)(N1 - t1) * N2;

  float2 z[12];
  #pragma unroll
  for (int m = 0; m < 12; ++m) {
    float re = pre[(m << 6) + l];
    float im = special ? 0.0f : pim[(m << 6) + l];
    z[m] = make_float2(re, im);
  }

  float2 A[3][4];
  #pragma unroll
  for (int q = 0; q < 3; ++q) {
    float2 s0 = z[q], s1 = z[3+q], s2 = z[6+q], s3 = z[9+q];
    float2 t0 = cadd(s0,s2), t1v = csub(s0,s2);
    float2 t2 = cadd(s1,s3), t3 = cnegi(csub(s1,s3));
    A[q][0] = cadd(t0,t2); A[q][1] = cadd(t1v,t3);
    A[q][2] = csub(t0,t2); A[q][3] = csub(t1v,t3);
  }
  const float h3 = 0.8660254037844386f;
  const float2 W1[4] = { {1.f,0.f}, {h3,-0.5f}, {0.5f,-h3}, {0.f,-1.f} };
  const float2 W2[4] = { {1.f,0.f}, {0.5f,-h3}, {-0.5f,-h3}, {-1.f,0.f} };
  float2 y[12];
  #pragma unroll
  for (int k4 = 0; k4 < 4; ++k4) {
    float2 C0 = A[0][k4];
    float2 C1 = cmul(A[1][k4], W1[k4]);
    float2 C2 = cmul(A[2][k4], W2[k4]);
    float2 tt = cadd(C1,C2), d = csub(C1,C2);
    float2 u  = make_float2(C0.x - 0.5f*tt.x, C0.y - 0.5f*tt.y);
    float2 idd = make_float2(h3*d.y, -h3*d.x);
    y[k4]   = cadd(C0, tt);
    y[k4+4] = cadd(u, idd);
    y[k4+8] = csub(u, idd);
  }

  float base = -6.283185307179586f * (float)l / 768.0f;
  #pragma unroll
  for (int km = 1; km < 12; ++km) {
    float sn, cs; __sincosf(base * (float)km, &sn, &cs);
    y[km] = cmul(y[km], make_float2(cs, sn));
  }

  #pragma unroll
  for (int st = 0; st < 6; ++st) {
    int h = 32 >> st;
    int j = l & (h - 1);
    float sn, cs; __sincosf(-3.14159265358979f * (float)j / (float)h, &sn, &cs);
    float2 w = make_float2(cs, sn);
    bool hi = (l & h) != 0;
    #pragma unroll
    for (int m = 0; m < 12; ++m) {
      float px = __shfl_xor(y[m].x, h, 64);
      float py = __shfl_xor(y[m].y, h, 64);
      float2 p = make_float2(px, py);
      float2 lo  = cadd(y[m], p);
      float2 hiv = cmul(csub(p, y[m]), w);
      y[m] = hi ? hiv : lo;
    }
  }

  int r = ((l&1)<<5)|((l&2)<<3)|((l&4)<<1)|((l&8)>>1)|((l&16)>>3)|((l&32)>>5);
  float* Tb = T[grp];
  #pragma unroll
  for (int km = 0; km < 12; ++km) Tb[km*69 + r] = y[km].x;
  __syncthreads();

  #pragma unroll
  for (int mp = 0; mp < 12; ++mp) {
    int k = (mp << 6) + l;
    float v = Tb[(k % 12)*69 + (k / 12)];
    pre[k] = v;
    if (!special) pim[(N2 - k) % N2] = v;
  }
}

extern "C" void kernel_launch(void* const* d_in, const int* in_sizes, int n_in,
                              void* d_out, int out_size, void* d_ws, size_t ws_size,
                              hipStream_t stream) {
  const float* x = (const float*)d_in[0];
  float* out = (float*)d_out;
  if (ws_size >= WS_NEEDED) {
    float2* ws = (float2*)d_ws;
    p1a_kernel<<<dim3(3072), dim3(512), 0, stream>>>(x, ws);
    p1b_kernel<<<dim3(1536), dim3(1024), 0, stream>>>(ws, out);
  } else {
    (void)hipFuncSetAttribute(reinterpret_cast<const void*>(&fft_seq_fused),
                              hipFuncAttributeMaxDynamicSharedMemorySize,
                              4 * CPBUF * (int)sizeof(float2));
    fft_seq_fused<<<dim3(768), dim3(1024), 4 * CPBUF * sizeof(float2), stream>>>(x, out);
  }
  fft_hid_kernel<<<dim3(4098), dim3(256), 0, stream>>>(out);
}